// Round 2
// baseline (243.268 us; speedup 1.0000x reference)
//
#include <hip/hip_runtime.h>

// DilatedCausalSelfAttention on MI355X (gfx950)
// x:(4,8192,1024) f32 -> take every 4th row of each 2048 segment (16 seqs x 512 tokens),
// QKV proj (bf16 MFMA), 16-head causal attention (dh=64), out proj, scatter back, zeros elsewhere.
// ws layout (88 MB total):
//   xi_bf   [8192][1024] bf16   @ 0          (16 MB)
//   win_bf  [3072][1024] bf16   @ 16777216   (6 MB)
//   wout_bf [1024][1024] bf16   @ 23068672   (2 MB)
//   qkv     [8192][3072] bf16   @ 25165824   (48 MB)
//   o_bf    [8192][1024] bf16   @ 75497472   (16 MB)

typedef unsigned short u16;
typedef short short8 __attribute__((ext_vector_type(8)));
typedef float f32x4 __attribute__((ext_vector_type(4)));

__device__ __forceinline__ u16 f2bf(float f) {
  unsigned u = __builtin_bit_cast(unsigned, f);
  u += 0x7FFFu + ((u >> 16) & 1u);   // RNE
  return (u16)(u >> 16);
}

__device__ __forceinline__ void gload_lds16(const void* g, void* l) {
  __builtin_amdgcn_global_load_lds((const __attribute__((address_space(1))) void*)g,
                                   (__attribute__((address_space(3))) void*)l,
                                   16, 0, 0);
}

// ---------------- zero output ----------------
__global__ void zero_f4(float4* __restrict__ p, int n4) {
  int stride = gridDim.x * blockDim.x;
  for (int i = blockIdx.x * blockDim.x + threadIdx.x; i < n4; i += stride)
    p[i] = make_float4(0.f, 0.f, 0.f, 0.f);
}

// ---------------- gather x rows (every 4th) + f32->bf16 ----------------
__global__ void conv_gather(const float* __restrict__ x, u16* __restrict__ xi) {
  int t = blockIdx.x * 256 + threadIdx.x;            // 1,048,576 threads, 8 elems each
  if (t >= (8192 * 1024) / 8) return;
  int row = t >> 7;                                   // token index 0..8191
  int col = (t & 127) << 3;
  size_t src = ((size_t)((row >> 9) << 11) + ((row & 511) << 2)) * 1024 + col;
  float4 v0 = *(const float4*)(x + src);
  float4 v1 = *(const float4*)(x + src + 4);
  short8 o;
  o[0] = f2bf(v0.x); o[1] = f2bf(v0.y); o[2] = f2bf(v0.z); o[3] = f2bf(v0.w);
  o[4] = f2bf(v1.x); o[5] = f2bf(v1.y); o[6] = f2bf(v1.z); o[7] = f2bf(v1.w);
  *(short8*)(xi + (size_t)row * 1024 + col) = o;
}

// ---------------- plain f32->bf16 convert ----------------
__global__ void conv_plain(const float* __restrict__ in, u16* __restrict__ out, int n8) {
  int t = blockIdx.x * 256 + threadIdx.x;
  if (t >= n8) return;
  size_t base = (size_t)t * 8;
  float4 v0 = *(const float4*)(in + base);
  float4 v1 = *(const float4*)(in + base + 4);
  short8 o;
  o[0] = f2bf(v0.x); o[1] = f2bf(v0.y); o[2] = f2bf(v0.z); o[3] = f2bf(v0.w);
  o[4] = f2bf(v1.x); o[5] = f2bf(v1.y); o[6] = f2bf(v1.z); o[7] = f2bf(v1.w);
  *(short8*)(out + base) = o;
}

// ---------------- GEMM: C[m][n] = sum_k A[m][k]*B[n][k] + bias[n] ----------------
// A: M x K bf16 row-major, B: N x K bf16 row-major (B^T form).
// MODE 0: store bf16 to Cout[m*N + n]   (QKV)
// MODE 1: store f32 to d_out[((m/512)*2048 + (m%512)*4)*1024 + n]   (final, scatter)
template <int MODE>
__global__ __launch_bounds__(256) void gemm_bt(
    const u16* __restrict__ A, const u16* __restrict__ B,
    const float* __restrict__ bias, void* __restrict__ Cout,
    int M, int N, int K) {
  __shared__ u16 As[128 * 32];
  __shared__ u16 Bs[128 * 32];
  const int tid = threadIdx.x;
  const int w = tid >> 6, lane = tid & 63;
  const int wr = w >> 1, wc = w & 1;
  const int g = lane >> 4, lq = lane & 15;
  const int m0 = blockIdx.x * 128, n0 = blockIdx.y * 128;
  const int sr = w * 16 + (lane >> 2);   // staging row within 64-row half
  const int sc = (lane & 3) * 8;         // staging col (elements)
  f32x4 acc[4][4] = {};

  for (int k0 = 0; k0 < K; k0 += 32) {
    gload_lds16(A + (size_t)(m0 + sr) * K + k0 + sc,      &As[sr * 32 + sc]);
    gload_lds16(A + (size_t)(m0 + 64 + sr) * K + k0 + sc, &As[(64 + sr) * 32 + sc]);
    gload_lds16(B + (size_t)(n0 + sr) * K + k0 + sc,      &Bs[sr * 32 + sc]);
    gload_lds16(B + (size_t)(n0 + 64 + sr) * K + k0 + sc, &Bs[(64 + sr) * 32 + sc]);
    __syncthreads();   // drains vmcnt for global_load_lds

    short8 af[4], bf[4];
#pragma unroll
    for (int i = 0; i < 4; ++i) {
      af[i] = *reinterpret_cast<const short8*>(&As[(wr * 64 + i * 16 + lq) * 32 + g * 8]);
      bf[i] = *reinterpret_cast<const short8*>(&Bs[(wc * 64 + i * 16 + lq) * 32 + g * 8]);
    }
#pragma unroll
    for (int mi = 0; mi < 4; ++mi)
#pragma unroll
      for (int ni = 0; ni < 4; ++ni)
        acc[mi][ni] = __builtin_amdgcn_mfma_f32_16x16x32_bf16(af[mi], bf[ni], acc[mi][ni], 0, 0, 0);
    __syncthreads();
  }

#pragma unroll
  for (int mi = 0; mi < 4; ++mi) {
#pragma unroll
    for (int ni = 0; ni < 4; ++ni) {
      const int col = n0 + wc * 64 + ni * 16 + lq;
      const float bv = bias[col];
#pragma unroll
      for (int r = 0; r < 4; ++r) {
        const int m = m0 + wr * 64 + mi * 16 + g * 4 + r;
        const float v = acc[mi][ni][r] + bv;
        if (MODE == 0) {
          ((u16*)Cout)[(size_t)m * N + col] = f2bf(v);
        } else {
          const int orow = ((m >> 9) << 11) + ((m & 511) << 2);
          ((float*)Cout)[(size_t)orow * 1024 + col] = v;
        }
      }
    }
  }
}

// ---------------- attention ----------------
// grid: 2048 blocks = 16 bs * 16 h * 8 qgroups; 256 threads (4 waves).
// Each wave owns one 16-row Q-tile (qt = qg*4 + w). K/V staged per 128-row chunk.
__global__ __launch_bounds__(256) void attn_kernel(const u16* __restrict__ qkv,
                                                   u16* __restrict__ o_ws) {
  __shared__ u16 Ks[128][72];    // K rows, padded (row=144B, 16B-aligned)
  __shared__ u16 Vt[64][136];    // V transposed [d][k], padded (row=272B)
  __shared__ u16 Pl[4][16][40];  // per-wave P tile [q][k0..31], padded

  const int tid = threadIdx.x;
  const int w = tid >> 6, lane = tid & 63;
  const int g = lane >> 4, lq = lane & 15;
  const int bid = blockIdx.x;
  const int bs = bid >> 7, h = (bid >> 3) & 15, qg = bid & 7;

  const u16* baseq = qkv + (size_t)bs * 512 * 3072 + h * 64;
  const u16* basek = baseq + 1024;
  const u16* basev = baseq + 2048;

  const int qt = qg * 4 + w;
  const int q0 = qt * 16;
  const int kmax_w = q0 + 16;    // exclusive causal bound for this wave

  // Q fragments (reused over all k): a[j] = Q[q0+lq][dstep*32 + g*8 + j]
  short8 qf0 = *reinterpret_cast<const short8*>(baseq + (size_t)(q0 + lq) * 3072 + g * 8);
  short8 qf1 = *reinterpret_cast<const short8*>(baseq + (size_t)(q0 + lq) * 3072 + 32 + g * 8);

  float m_r[4] = {-1e30f, -1e30f, -1e30f, -1e30f};
  float l_r[4] = {0.f, 0.f, 0.f, 0.f};
  f32x4 oacc[4] = {};

  const int nchunks = (qg >> 1) + 1;   // K rows needed by group = qg*64+64
  for (int c = 0; c < nchunks; ++c) {
    const int kb0 = c * 128;
    // stage K chunk: 128 rows x 64 cols  (1024 short8 loads across 256 threads)
#pragma unroll
    for (int i = 0; i < 4; ++i) {
      int s = tid + i * 256;
      int r = s >> 3, c8 = (s & 7) * 8;
      *reinterpret_cast<short8*>(&Ks[r][c8]) =
          *reinterpret_cast<const short8*>(basek + (size_t)(kb0 + r) * 3072 + c8);
    }
    // stage V chunk transposed: Vt[d][k]
#pragma unroll
    for (int i = 0; i < 4; ++i) {
      int s = tid + i * 256;
      int r = s >> 3, c8 = (s & 7) * 8;
      short8 v = *reinterpret_cast<const short8*>(basev + (size_t)(kb0 + r) * 3072 + c8);
#pragma unroll
      for (int j = 0; j < 8; ++j) Vt[c8 + j][r] = (u16)v[j];
    }
    __syncthreads();

    for (int kb = 0; kb < 128; kb += 32) {
      const int kg = kb0 + kb;
      if (kg >= kmax_w) break;   // wave-uniform causal skip
      // S = Q K^T for cols [kg, kg+32)
      f32x4 s0 = {}, s1 = {};
      short8 k00 = *reinterpret_cast<const short8*>(&Ks[kb + lq][g * 8]);
      short8 k01 = *reinterpret_cast<const short8*>(&Ks[kb + lq][32 + g * 8]);
      s0 = __builtin_amdgcn_mfma_f32_16x16x32_bf16(qf0, k00, s0, 0, 0, 0);
      s0 = __builtin_amdgcn_mfma_f32_16x16x32_bf16(qf1, k01, s0, 0, 0, 0);
      short8 k10 = *reinterpret_cast<const short8*>(&Ks[kb + 16 + lq][g * 8]);
      short8 k11 = *reinterpret_cast<const short8*>(&Ks[kb + 16 + lq][32 + g * 8]);
      s1 = __builtin_amdgcn_mfma_f32_16x16x32_bf16(qf0, k10, s1, 0, 0, 0);
      s1 = __builtin_amdgcn_mfma_f32_16x16x32_bf16(qf1, k11, s1, 0, 0, 0);

      float p0[4], p1[4];
#pragma unroll
      for (int r = 0; r < 4; ++r) {
        const int q = q0 + g * 4 + r;   // C-layout row
        float a = s0[r] * 0.125f;
        float b = s1[r] * 0.125f;
        if (kg + lq > q) a = -1e30f;          // causal mask
        if (kg + 16 + lq > q) b = -1e30f;
        float pm = fmaxf(a, b);
        pm = fmaxf(pm, __shfl_xor(pm, 1));
        pm = fmaxf(pm, __shfl_xor(pm, 2));
        pm = fmaxf(pm, __shfl_xor(pm, 4));
        pm = fmaxf(pm, __shfl_xor(pm, 8));
        const float mn = fmaxf(m_r[r], pm);
        const float sc = __expf(m_r[r] - mn);
        m_r[r] = mn;
        a = __expf(a - mn);
        b = __expf(b - mn);
        float rs = a + b;
        rs += __shfl_xor(rs, 1);
        rs += __shfl_xor(rs, 2);
        rs += __shfl_xor(rs, 4);
        rs += __shfl_xor(rs, 8);
        l_r[r] = l_r[r] * sc + rs;
        oacc[0][r] *= sc; oacc[1][r] *= sc; oacc[2][r] *= sc; oacc[3][r] *= sc;
        p0[r] = a; p1[r] = b;
      }
      // P (C-layout) -> LDS -> A-operand layout
#pragma unroll
      for (int r = 0; r < 4; ++r) {
        Pl[w][g * 4 + r][lq] = f2bf(p0[r]);
        Pl[w][g * 4 + r][16 + lq] = f2bf(p1[r]);
      }
      short8 pf = *reinterpret_cast<const short8*>(&Pl[w][lq][g * 8]);
#pragma unroll
      for (int dt = 0; dt < 4; ++dt) {
        short8 vf = *reinterpret_cast<const short8*>(&Vt[dt * 16 + lq][kb + g * 8]);
        oacc[dt] = __builtin_amdgcn_mfma_f32_16x16x32_bf16(pf, vf, oacc[dt], 0, 0, 0);
      }
    }
    __syncthreads();
  }

#pragma unroll
  for (int r = 0; r < 4; ++r) {
    const float inv = 1.0f / l_r[r];
    const int q = q0 + g * 4 + r;
    u16* dst = o_ws + (size_t)(bs * 512 + q) * 1024 + h * 64;
#pragma unroll
    for (int dt = 0; dt < 4; ++dt) dst[dt * 16 + lq] = f2bf(oacc[dt][r] * inv);
  }
}

// ---------------- launch ----------------
extern "C" void kernel_launch(void* const* d_in, const int* in_sizes, int n_in,
                              void* d_out, int out_size, void* d_ws, size_t ws_size,
                              hipStream_t stream) {
  const float* x     = (const float*)d_in[0];   // 4*8192*1024
  const float* w_in  = (const float*)d_in[1];   // 3072*1024
  const float* b_in  = (const float*)d_in[2];   // 3072
  const float* w_out = (const float*)d_in[3];   // 1024*1024
  const float* b_out = (const float*)d_in[4];   // 1024

  char* ws = (char*)d_ws;
  u16* xi_bf   = (u16*)(ws);
  u16* win_bf  = (u16*)(ws + 16777216);
  u16* wout_bf = (u16*)(ws + 16777216 + 6291456);
  u16* qkv     = (u16*)(ws + 16777216 + 6291456 + 2097152);
  u16* o_bf    = (u16*)(ws + 16777216 + 6291456 + 2097152 + 50331648);

  // 1. zero entire output (non-selected rows must be 0; harness poisons d_out)
  zero_f4<<<2048, 256, 0, stream>>>((float4*)d_out, (4 * 8192 * 1024) / 4);
  // 2. convert inputs to bf16
  conv_gather<<<4096, 256, 0, stream>>>(x, xi_bf);
  conv_plain<<<1536, 256, 0, stream>>>(w_in, win_bf, (3072 * 1024) / 8);
  conv_plain<<<512, 256, 0, stream>>>(w_out, wout_bf, (1024 * 1024) / 8);
  // 3. QKV projection: (8192x1024) @ (3072x1024)^T + b_in -> qkv bf16
  gemm_bt<0><<<dim3(64, 24), 256, 0, stream>>>(xi_bf, win_bf, b_in, qkv, 8192, 3072, 1024);
  // 4. attention -> o_bf
  attn_kernel<<<2048, 256, 0, stream>>>(qkv, o_bf);
  // 5. output projection + scatter: (8192x1024) @ (1024x1024)^T + b_out -> d_out rows 0::4
  gemm_bt<1><<<dim3(64, 8), 256, 0, stream>>>(o_bf, wout_bf, b_out, d_out, 8192, 1024, 1024);
}